// Round 7
// baseline (109.353 us; speedup 1.0000x reference)
//
#include <hip/hip_runtime.h>

// Split design:
//  Kernel 1 (dot_kernel): pure streaming. 8 lanes/row, 8 rows/wave-iter,
//    64 rows/wave, guard-free (B % 256 == 0 checked on host). Product dot in
//    log2 space (v_log_f32), sum dot f32, 3-step butterfly in 8-lane groups,
//    in-register transpose via broadcast-shfl, coalesced float2 store of raw
//    (p, s) to d_ws. Low VGPR, no transcendental tail -> max occupancy, the
//    load stream never stalls on the chain.
//  Kernel 2 (chain_kernel): 1 row/thread, reads (p,s), runs exp2 + 5-stage
//    libm chain, writes out. ~12 MB traffic, trivially parallel.
// Fallback fused kernel (R6 structure) if ws_size is too small.

__global__ __launch_bounds__(256) void dot_kernel(
    const float* __restrict__ x,
    const float* __restrict__ W_prod,
    const float* __restrict__ W_sum,
    float2* __restrict__ ps)
{
    const int tid  = threadIdx.x;
    const int lane = tid & 63;
    const int wid  = tid >> 6;
    const int u    = lane & 7;      // sub-lane within 8-lane row group
    const int g    = lane >> 3;     // row group (0..7)

    float4 wp[4], ws[4];
    #pragma unroll
    for (int j = 0; j < 4; ++j) {
        wp[j] = reinterpret_cast<const float4*>(W_prod)[u + 8 * j];
        ws[j] = reinterpret_cast<const float4*>(W_sum)[u + 8 * j];
    }

    const int wbase = (blockIdx.x * 4 + wid) * 64;   // this wave's 64-row tile

    float pr = 0.0f, sr = 0.0f;
    #pragma unroll
    for (int it = 0; it < 8; ++it) {
        const int row = wbase + it * 8 + g;
        const float4* xr = reinterpret_cast<const float4*>(x + (size_t)row * 128);
        float4 xv[4];
        #pragma unroll
        for (int j = 0; j < 4; ++j) xv[j] = xr[u + 8 * j];
        float p = 0.0f, s = 0.0f;
        #pragma unroll
        for (int j = 0; j < 4; ++j) {
            p += __log2f(__builtin_fabsf(xv[j].x)) * wp[j].x;
            p += __log2f(__builtin_fabsf(xv[j].y)) * wp[j].y;
            p += __log2f(__builtin_fabsf(xv[j].z)) * wp[j].z;
            p += __log2f(__builtin_fabsf(xv[j].w)) * wp[j].w;
            s += xv[j].x * ws[j].x + xv[j].y * ws[j].y
               + xv[j].z * ws[j].z + xv[j].w * ws[j].w;
        }
        #pragma unroll
        for (int m = 4; m >= 1; m >>= 1) {   // stays in 8-lane group
            p += __shfl_xor(p, m, 64);
            s += __shfl_xor(s, m, 64);
        }
        const float pb = __shfl(p, (lane & 7) * 8, 64);
        const float sb = __shfl(s, (lane & 7) * 8, 64);
        if (g == it) { pr = pb; sr = sb; }
    }
    ps[wbase + lane] = make_float2(pr, sr);   // coalesced 512B/wave
}

__global__ __launch_bounds__(256) void chain_kernel(
    const float2* __restrict__ ps,
    const float* __restrict__ b_prod, const float* __restrict__ W_sum,
    const float* __restrict__ b_sum,
    const float* __restrict__ w_dln,  const float* __restrict__ W_ln,
    const float* __restrict__ w_dsin, const float* __restrict__ W_sin,
    const float* __restrict__ w_dcos, const float* __restrict__ W_cos,
    const float* __restrict__ w_de,   const float* __restrict__ W_e,
    const float* __restrict__ w_dtanh,const float* __restrict__ W_tanh,
    float* __restrict__ out, int B)
{
    const int i = blockIdx.x * 256 + threadIdx.x;
    if (i >= B) return;
    const float2 v = ps[i];
    const float bp2 = b_prod[0] * 1.44269504088896340736f;
    const float x_prod = __builtin_amdgcn_exp2f(v.x + bp2);
    float h = v.y + x_prod * W_sum[128] + b_sum[0];
    float d;
    d = fmaxf(logf(fabsf(h)) * w_dln[0], 0.0f);   h = d * W_ln[0]   + h * W_ln[1];
    d = fmaxf(sinf(h) * w_dsin[0], 0.0f);         h = d * W_sin[0]  + h * W_sin[1];
    d = fmaxf(cosf(h) * w_dcos[0], 0.0f);         h = d * W_cos[0]  + h * W_cos[1];
    d = fmaxf(expf(h) * w_de[0],   0.0f);         h = d * W_e[0]    + h * W_e[1];
    d = fmaxf(tanhf(h) * w_dtanh[0], 0.0f);       h = d * W_tanh[0] + h * W_tanh[1];
    out[i] = h;
}

// ---- Fallback: fused single-kernel path (R6 structure, guarded) ----
__global__ __launch_bounds__(256) void fused_kernel(
    const float* __restrict__ x,
    const float* __restrict__ W_prod, const float* __restrict__ b_prod,
    const float* __restrict__ W_sum,  const float* __restrict__ b_sum,
    const float* __restrict__ w_dln,  const float* __restrict__ W_ln,
    const float* __restrict__ w_dsin, const float* __restrict__ W_sin,
    const float* __restrict__ w_dcos, const float* __restrict__ W_cos,
    const float* __restrict__ w_de,   const float* __restrict__ W_e,
    const float* __restrict__ w_dtanh,const float* __restrict__ W_tanh,
    float* __restrict__ out, int B)
{
    const int tid  = threadIdx.x;
    const int lane = tid & 63;
    const int wid  = tid >> 6;
    const int u    = lane & 7;
    const int g    = lane >> 3;
    float4 wp[4], ws[4];
    #pragma unroll
    for (int j = 0; j < 4; ++j) {
        wp[j] = reinterpret_cast<const float4*>(W_prod)[u + 8 * j];
        ws[j] = reinterpret_cast<const float4*>(W_sum)[u + 8 * j];
    }
    const float ws128 = W_sum[128];
    const float bp2 = b_prod[0] * 1.44269504088896340736f;
    const float bs = b_sum[0];
    const int wbase = (blockIdx.x * 4 + wid) * 64;
    float pr = 0.0f, sr = 0.0f;
    #pragma unroll 4
    for (int it = 0; it < 8; ++it) {
        const int row = wbase + it * 8 + g;
        float p = 0.0f, s = 0.0f;
        if (row < B) {
            const float4* xr = reinterpret_cast<const float4*>(x + (size_t)row * 128);
            float4 xv[4];
            #pragma unroll
            for (int j = 0; j < 4; ++j) xv[j] = xr[u + 8 * j];
            #pragma unroll
            for (int j = 0; j < 4; ++j) {
                p += __log2f(__builtin_fabsf(xv[j].x)) * wp[j].x;
                p += __log2f(__builtin_fabsf(xv[j].y)) * wp[j].y;
                p += __log2f(__builtin_fabsf(xv[j].z)) * wp[j].z;
                p += __log2f(__builtin_fabsf(xv[j].w)) * wp[j].w;
                s += xv[j].x * ws[j].x + xv[j].y * ws[j].y
                   + xv[j].z * ws[j].z + xv[j].w * ws[j].w;
            }
        }
        #pragma unroll
        for (int m = 4; m >= 1; m >>= 1) {
            p += __shfl_xor(p, m, 64);
            s += __shfl_xor(s, m, 64);
        }
        const float pb = __shfl(p, (lane & 7) * 8, 64);
        const float sb = __shfl(s, (lane & 7) * 8, 64);
        if (g == it) { pr = pb; sr = sb; }
    }
    const float x_prod = __builtin_amdgcn_exp2f(pr + bp2);
    float h = sr + x_prod * ws128 + bs;
    float d;
    d = fmaxf(logf(fabsf(h)) * w_dln[0], 0.0f);   h = d * W_ln[0]   + h * W_ln[1];
    d = fmaxf(sinf(h) * w_dsin[0], 0.0f);         h = d * W_sin[0]  + h * W_sin[1];
    d = fmaxf(cosf(h) * w_dcos[0], 0.0f);         h = d * W_cos[0]  + h * W_cos[1];
    d = fmaxf(expf(h) * w_de[0],   0.0f);         h = d * W_e[0]    + h * W_e[1];
    d = fmaxf(tanhf(h) * w_dtanh[0], 0.0f);       h = d * W_tanh[0] + h * W_tanh[1];
    const int orow = wbase + lane;
    if (orow < B) out[orow] = h;
}

extern "C" void kernel_launch(void* const* d_in, const int* in_sizes, int n_in,
                              void* d_out, int out_size, void* d_ws, size_t ws_size,
                              hipStream_t stream) {
    const float* x      = (const float*)d_in[0];
    const float* W_prod = (const float*)d_in[1];
    const float* b_prod = (const float*)d_in[2];
    const float* W_sum  = (const float*)d_in[3];
    const float* b_sum  = (const float*)d_in[4];
    const float* w_dln  = (const float*)d_in[5];
    const float* W_ln   = (const float*)d_in[6];
    const float* w_dsin = (const float*)d_in[7];
    const float* W_sin  = (const float*)d_in[8];
    const float* w_dcos = (const float*)d_in[9];
    const float* W_cos  = (const float*)d_in[10];
    const float* w_de   = (const float*)d_in[11];
    const float* W_e    = (const float*)d_in[12];
    const float* w_dtanh= (const float*)d_in[13];
    const float* W_tanh = (const float*)d_in[14];
    float* out = (float*)d_out;

    const int B = out_size;   // 1048576
    const bool split_ok = (ws_size >= (size_t)B * sizeof(float2)) && (B % 256 == 0);

    if (split_ok) {
        float2* ps = (float2*)d_ws;
        hipLaunchKernelGGL(dot_kernel, dim3(B / 256), dim3(256), 0, stream,
                           x, W_prod, W_sum, ps);
        hipLaunchKernelGGL(chain_kernel, dim3(B / 256), dim3(256), 0, stream,
                           ps, b_prod, W_sum, b_sum,
                           w_dln, W_ln, w_dsin, W_sin, w_dcos, W_cos,
                           w_de, W_e, w_dtanh, W_tanh, out, B);
    } else {
        hipLaunchKernelGGL(fused_kernel, dim3((B + 255) / 256), dim3(256), 0, stream,
                           x, W_prod, b_prod, W_sum, b_sum,
                           w_dln, W_ln, w_dsin, W_sin, w_dcos, W_cos,
                           w_de, W_e, w_dtanh, W_tanh, out, B);
    }
}

// Round 9
// 86.664 us; speedup vs baseline: 1.2618x; 1.2618x over previous
//
#include <hip/hip_runtime.h>

// R6 structure + non-temporal (streaming) loads/stores. x is read-once
// (512 MB, 2x the 256 MB L3): nt loads avoid L2/L3 allocation so the line
// never round-trips the cache hierarchy. 8 lanes per row, 8 rows per
// wave-iteration, 64 rows per wave, barrier-free, LDS-free. Product dot in
// log2 space (v_log_f32), sum dot f32; 3-step butterfly within 8-lane
// groups; in-register transpose via broadcast shfl; chain wave-parallel.
// Note: __builtin_nontemporal_load needs a clang native vector type, not
// HIP's struct float4 -> use ext_vector_type(4).

typedef float floatx4 __attribute__((ext_vector_type(4)));

__global__ __launch_bounds__(256) void funcblock_kernel(
    const float* __restrict__ x,
    const float* __restrict__ W_prod, const float* __restrict__ b_prod,
    const float* __restrict__ W_sum,  const float* __restrict__ b_sum,
    const float* __restrict__ w_dln,  const float* __restrict__ W_ln,
    const float* __restrict__ w_dsin, const float* __restrict__ W_sin,
    const float* __restrict__ w_dcos, const float* __restrict__ W_cos,
    const float* __restrict__ w_de,   const float* __restrict__ W_e,
    const float* __restrict__ w_dtanh,const float* __restrict__ W_tanh,
    float* __restrict__ out, int B)
{
    const int tid  = threadIdx.x;
    const int lane = tid & 63;
    const int wid  = tid >> 6;      // wave in block (0..3)
    const int u    = lane & 7;      // sub-lane within 8-lane row group
    const int g    = lane >> 3;     // row group (0..7)

    floatx4 wp[4], ws[4];
    #pragma unroll
    for (int j = 0; j < 4; ++j) {
        wp[j] = reinterpret_cast<const floatx4*>(W_prod)[u + 8 * j];
        ws[j] = reinterpret_cast<const floatx4*>(W_sum)[u + 8 * j];
    }
    const float ws128 = W_sum[128];
    const float bp2 = b_prod[0] * 1.44269504088896340736f;  // exp -> exp2 fold
    const float bs = b_sum[0];
    const float wdln  = w_dln[0],  wln0  = W_ln[0],  wln1  = W_ln[1];
    const float wdsin = w_dsin[0], wsin0 = W_sin[0], wsin1 = W_sin[1];
    const float wdcos = w_dcos[0], wcos0 = W_cos[0], wcos1 = W_cos[1];
    const float wde   = w_de[0],   we0   = W_e[0],   we1   = W_e[1];
    const float wdtanh= w_dtanh[0],wt0   = W_tanh[0],wt1   = W_tanh[1];

    const int wbase = (blockIdx.x * 4 + wid) * 64;   // this wave's 64-row tile

    float pr = 0.0f, sr = 0.0f;
    #pragma unroll 4
    for (int it = 0; it < 8; ++it) {
        const int row = wbase + it * 8 + g;
        float p = 0.0f, s = 0.0f;
        if (row < B) {
            const floatx4* xr =
                reinterpret_cast<const floatx4*>(x + (size_t)row * 128);
            floatx4 xv[4];
            #pragma unroll
            for (int j = 0; j < 4; ++j)
                xv[j] = __builtin_nontemporal_load(&xr[u + 8 * j]);  // nt read
            #pragma unroll
            for (int j = 0; j < 4; ++j) {
                p += __log2f(__builtin_fabsf(xv[j].x)) * wp[j].x;
                p += __log2f(__builtin_fabsf(xv[j].y)) * wp[j].y;
                p += __log2f(__builtin_fabsf(xv[j].z)) * wp[j].z;
                p += __log2f(__builtin_fabsf(xv[j].w)) * wp[j].w;
                s += xv[j].x * ws[j].x + xv[j].y * ws[j].y
                   + xv[j].z * ws[j].z + xv[j].w * ws[j].w;
            }
        }
        #pragma unroll
        for (int m = 4; m >= 1; m >>= 1) {   // 3 steps, stays in 8-lane group
            p += __shfl_xor(p, m, 64);
            s += __shfl_xor(s, m, 64);
        }
        const float pb = __shfl(p, (lane & 7) * 8, 64);
        const float sb = __shfl(s, (lane & 7) * 8, 64);
        if (g == it) { pr = pb; sr = sb; }
    }

    // ---- Chain: 64 rows, one per lane, all lanes active ----
    const float x_prod = __builtin_amdgcn_exp2f(pr + bp2);   // v_exp_f32
    float h = sr + x_prod * ws128 + bs;
    float d;
    d = fmaxf(logf(fabsf(h)) * wdln, 0.0f);  h = d * wln0  + h * wln1;
    d = fmaxf(sinf(h) * wdsin, 0.0f);        h = d * wsin0 + h * wsin1;
    d = fmaxf(cosf(h) * wdcos, 0.0f);        h = d * wcos0 + h * wcos1;
    d = fmaxf(expf(h) * wde,   0.0f);        h = d * we0   + h * we1;
    d = fmaxf(tanhf(h) * wdtanh, 0.0f);      h = d * wt0   + h * wt1;
    const int orow = wbase + lane;
    if (orow < B) __builtin_nontemporal_store(h, &out[orow]);  // nt write
}

extern "C" void kernel_launch(void* const* d_in, const int* in_sizes, int n_in,
                              void* d_out, int out_size, void* d_ws, size_t ws_size,
                              hipStream_t stream) {
    const float* x      = (const float*)d_in[0];
    const float* W_prod = (const float*)d_in[1];
    const float* b_prod = (const float*)d_in[2];
    const float* W_sum  = (const float*)d_in[3];
    const float* b_sum  = (const float*)d_in[4];
    const float* w_dln  = (const float*)d_in[5];
    const float* W_ln   = (const float*)d_in[6];
    const float* w_dsin = (const float*)d_in[7];
    const float* W_sin  = (const float*)d_in[8];
    const float* w_dcos = (const float*)d_in[9];
    const float* W_cos  = (const float*)d_in[10];
    const float* w_de   = (const float*)d_in[11];
    const float* W_e    = (const float*)d_in[12];
    const float* w_dtanh= (const float*)d_in[13];
    const float* W_tanh = (const float*)d_in[14];
    float* out = (float*)d_out;

    const int B = out_size;                 // 1048576 rows
    const int block = 256;                  // 4 waves, 64 rows each
    const int grid  = (B + 255) / 256;      // 4096 blocks, covers B exactly

    hipLaunchKernelGGL(funcblock_kernel, dim3(grid), dim3(block), 0, stream,
                       x, W_prod, b_prod, W_sum, b_sum,
                       w_dln, W_ln, w_dsin, W_sin, w_dcos, W_cos,
                       w_de, W_e, w_dtanh, W_tanh, out, B);
}